// Round 2
// baseline (141.792 us; speedup 1.0000x reference)
//
#include <hip/hip_runtime.h>
#include <cstdint>
#include <cmath>

#define D_DIM 2048
#define E_DIM 64
#define N_TOK 16384
#define K_TOP 8
#define DK 64
#define KCHUNKS (D_DIM / DK)  // 32
#define TPB 32                // tokens per block
#define TPW 8                 // tokens per wave

// lane = expert (E=64 == wave size). Wave computes logits for 8 tokens x 64 experts,
// then does wave-wide top-8 + softmax + scatter per token.
__global__ __launch_bounds__(256, 2)
void router_kernel(const float* __restrict__ X, const float* __restrict__ W,
                   float* __restrict__ Pout, float* __restrict__ Mout) {
  __shared__ float xs[2][TPB][DK];    // 16 KB
  __shared__ float ws[2][E_DIM][DK];  // 32 KB

  const int tid = threadIdx.x;
  const int wave = tid >> 6;
  const int lane = tid & 63;
  const int tok0 = blockIdx.x * TPB;

  const int lrow = lane >> 4;   // 0..3: row within a 4-row staging call
  const int lcol = lane & 15;   // 16B chunk within a 64-float row

  float4 acc[TPW];
#pragma unroll
  for (int t = 0; t < TPW; ++t) acc[t] = make_float4(0.f, 0.f, 0.f, 0.f);

  // Stage one D-chunk of X [32][64] and W [64][64] into LDS via global_load_lds.
  // W source columns are pre-swizzled (chunk ^ (row&15)) so the per-lane
  // ds_read_b128 row-reads later are bank-conflict-free (linear LDS dest
  // requirement of global_load_lds -> swizzle the GLOBAL source instead).
  auto stage = [&](int k, int buf) {
#pragma unroll
    for (int c = 0; c < 2; ++c) {  // X: 8 rows per wave, 4 rows per call
      const int rb = (wave * 2 + c) * 4;
      const int row = rb + lrow;
      const float* g = X + (size_t)(tok0 + row) * D_DIM + k * DK + lcol * 4;
      __builtin_amdgcn_global_load_lds(
          (const __attribute__((address_space(1))) void*)g,
          (__attribute__((address_space(3))) void*)&xs[buf][rb][0], 16, 0, 0);
    }
#pragma unroll
    for (int c = 0; c < 4; ++c) {  // W: 16 rows per wave, 4 rows per call
      const int rb = wave * 16 + c * 4;
      const int e = rb + lrow;
      const int gc = (lcol ^ (e & 15)) * 4;  // pre-swizzled source column
      const float* g = W + (size_t)e * D_DIM + k * DK + gc;
      __builtin_amdgcn_global_load_lds(
          (const __attribute__((address_space(1))) void*)g,
          (__attribute__((address_space(3))) void*)&ws[buf][rb][0], 16, 0, 0);
    }
  };

  stage(0, 0);
  asm volatile("s_waitcnt vmcnt(0)" ::: "memory");
  __syncthreads();

  for (int k = 0; k < KCHUNKS; ++k) {
    const int buf = k & 1;
    if (k + 1 < KCHUNKS) stage(k + 1, buf ^ 1);

    // my expert's weights for this chunk -> 64 VGPRs (swizzled read)
    float4 wr[DK / 4];
#pragma unroll
    for (int dg = 0; dg < DK / 4; ++dg)
      wr[dg] = *(const float4*)&ws[buf][lane][(dg ^ lcol) * 4];

#pragma unroll
    for (int t = 0; t < TPW; ++t) {
      const float* xrow = &xs[buf][wave * TPW + t][0];
      float4 part = make_float4(0.f, 0.f, 0.f, 0.f);
#pragma unroll
      for (int dg = 0; dg < DK / 4; ++dg) {
        const float4 xv = *(const float4*)&xrow[dg * 4];  // LDS broadcast
        part.x = fmaf(wr[dg].x, xv.x, part.x);
        part.y = fmaf(wr[dg].y, xv.y, part.y);
        part.z = fmaf(wr[dg].z, xv.z, part.z);
        part.w = fmaf(wr[dg].w, xv.w, part.w);
      }
      // per-chunk partial -> shorter accumulation chains (tie-safety vs np ref)
      acc[t].x += part.x; acc[t].y += part.y;
      acc[t].z += part.z; acc[t].w += part.w;
    }
    asm volatile("s_waitcnt vmcnt(0)" ::: "memory");
    __syncthreads();
  }

  // epilogue: per token, logit lives in lane = expert
#pragma unroll
  for (int t = 0; t < TPW; ++t) {
    const int tok = tok0 + wave * TPW + t;
    float v = (acc[t].x + acc[t].y) + (acc[t].z + acc[t].w);

    float topv[K_TOP];
    int topi[K_TOP];
#pragma unroll
    for (int kk = 0; kk < K_TOP; ++kk) {
      float m = v;
#pragma unroll
      for (int off = 32; off > 0; off >>= 1)
        m = fmaxf(m, __shfl_xor(m, off, 64));
      const unsigned long long bal = __ballot(v == m);
      const int li = __ffsll(bal) - 1;  // lowest lane on ties == jax stable order
      topv[kk] = m;
      topi[kk] = li;
      if (lane == li) v = -INFINITY;
    }

    float p[K_TOP];
    float s = 0.f;
#pragma unroll
    for (int kk = 0; kk < K_TOP; ++kk) {
      p[kk] = expf(topv[kk] - topv[0]);
      s += p[kk];
    }
    const float inv = 1.f / s;

    float pv = 0.f, mv = 0.f;
#pragma unroll
    for (int kk = 0; kk < K_TOP; ++kk)
      if (topi[kk] == lane) { pv = p[kk] * inv; mv = 1.f; }

    Pout[(size_t)tok * E_DIM + lane] = pv;  // zeros where not selected
    Mout[(size_t)tok * E_DIM + lane] = mv;  // routing map as 0.0 / 1.0
  }
}

extern "C" void kernel_launch(void* const* d_in, const int* in_sizes, int n_in,
                              void* d_out, int out_size, void* d_ws, size_t ws_size,
                              hipStream_t stream) {
  const float* X = (const float*)d_in[0];
  const float* W = (const float*)d_in[1];
  float* P = (float*)d_out;
  float* M = P + (size_t)N_TOK * E_DIM;  // outputs concatenated: probs, then map
  router_kernel<<<dim3(N_TOK / TPB), dim3(256), 0, stream>>>(X, W, P, M);
}

// Round 4
// 67.650 us; speedup vs baseline: 2.0960x; 2.0960x over previous
//
#include <hip/hip_runtime.h>
#include <cstdint>
#include <cmath>

#define D_DIM 2048
#define E_DIM 64
#define N_TOK 16384
#define K_TOP 8
#define KSTEP 32
#define NSTEP 64      // 2048 / 32 k-steps
#define BLK_TOK 64    // tokens per block (4 waves x 16)
#define NFRAG 12      // 4 etiles x 3 terms (h,m,l)

typedef __attribute__((ext_vector_type(8))) short bf16x8;
typedef __attribute__((ext_vector_type(4))) float f32x4;

union U4 { uint4 u; bf16x8 s; };

// round-to-nearest-even-ish bf16 split: x = h + m + l + r, |r| <~ 2^-23 |x|
__device__ inline void split3_8(const float* a8, bf16x8& h, bf16x8& m, bf16x8& l) {
#pragma unroll
  for (int j = 0; j < 8; ++j) {
    const float x = a8[j];
    const unsigned u = __builtin_bit_cast(unsigned, x);
    const unsigned rh = (u + 0x7FFFu + ((u >> 16) & 1u)) & 0xFFFF0000u;
    h[j] = (short)(rh >> 16);
    const float r1 = x - __builtin_bit_cast(float, rh);
    const unsigned u1 = __builtin_bit_cast(unsigned, r1);
    const unsigned rm = (u1 + 0x7FFFu + ((u1 >> 16) & 1u)) & 0xFFFF0000u;
    m[j] = (short)(rm >> 16);
    const float r2 = r1 - __builtin_bit_cast(float, rm);
    l[j] = (short)(__builtin_bit_cast(unsigned, r2) >> 16);  // trunc, resid ~2^-23
  }
}

// Kernel 1: pre-split W [64][2048] into 3-term MFMA B-fragments in d_ws.
// WF[(ks*12 + et*3 + term)*64 + lane], term 0=h 1=m 2=l.
__global__ void wprep_kernel(const float* __restrict__ W, uint4* __restrict__ WF) {
  const int gid = blockIdx.x * 256 + threadIdx.x;  // 16384 = 64ks * 4et * 64lane
  const int lane = gid & 63;
  const int et = (gid >> 6) & 3;
  const int ks = gid >> 8;
  const int e = et * 16 + (lane & 15);
  const int kg = lane >> 4;
  const float* src = W + (size_t)e * D_DIM + ks * KSTEP + kg * 8;
  const float4 a = ((const float4*)src)[0];
  const float4 b = ((const float4*)src)[1];
  float a8[8] = {a.x, a.y, a.z, a.w, b.x, b.y, b.z, b.w};
  U4 h, m, l;
  split3_8(a8, h.s, m.s, l.s);
  const int fbase = (ks * NFRAG + et * 3) * 64 + lane;
  WF[fbase] = h.u;
  WF[fbase + 64] = m.u;
  WF[fbase + 128] = l.u;
}

struct Frags { float4 a0, a1; uint4 b[NFRAG]; };

// Kernel 2: fused GEMM (split-3 bf16 MFMA, 6 products) + top-8 + softmax + scatter.
__global__ __launch_bounds__(256)
void gemm_router(const float* __restrict__ X, const uint4* __restrict__ WF,
                 float* __restrict__ Pout, float* __restrict__ Mout) {
  __shared__ float xs[3][BLK_TOK][KSTEP];    // 24 KB (content XOR-swizzled by row)
  __shared__ uint4 wf4[3][NFRAG * 64];       // 36 KB, linear frag order

  const int tid = threadIdx.x;
  const int w = tid >> 6;
  const int l = tid & 63;
  const int col = l & 15;
  const int kg = l >> 4;
  const int tok0 = blockIdx.x * BLK_TOK;

  auto stage = [&](int s) {
    const int bb = s % 3;
#pragma unroll
    for (int c = 0; c < 2; ++c) {  // X: 8KB/step
      const int slot = c * 256 + tid;  // row=slot>>3, chunk=slot&7
      const int row = slot >> 3;
      const int chk = slot & 7;
      const float* g = X + (size_t)(tok0 + row) * D_DIM + s * KSTEP + ((chk ^ (row & 7)) << 2);
      __builtin_amdgcn_global_load_lds(
          (const __attribute__((address_space(1))) void*)g,
          (__attribute__((address_space(3))) void*)&xs[bb][c * 32 + w * 8][0], 16, 0, 0);
    }
#pragma unroll
    for (int c = 0; c < 3; ++c) {  // W frags: 12KB/step, fully linear
      const int slot = c * 256 + tid;
      const uint4* g = WF + (size_t)s * (NFRAG * 64) + slot;
      __builtin_amdgcn_global_load_lds(
          (const __attribute__((address_space(1))) void*)g,
          (__attribute__((address_space(3))) void*)&wf4[bb][c * 256 + w * 64], 16, 0, 0);
    }
  };

  f32x4 acc0[4], acc1[4];
#pragma unroll
  for (int et = 0; et < 4; ++et) { acc0[et] = (f32x4)0.f; acc1[et] = (f32x4)0.f; }

  const int xrow = w * 16 + col;
  const int c0 = (2 * kg) ^ (col & 7);
  const int c1 = (2 * kg + 1) ^ (col & 7);

  auto loadAB = [&](int bb, Frags& f) {
    f.a0 = *(const float4*)&xs[bb][xrow][c0 << 2];
    f.a1 = *(const float4*)&xs[bb][xrow][c1 << 2];
#pragma unroll
    for (int i = 0; i < NFRAG; ++i) f.b[i] = wf4[bb][i * 64 + l];
  };

  auto crunch = [&](const Frags& f) {
    float a8[8] = {f.a0.x, f.a0.y, f.a0.z, f.a0.w, f.a1.x, f.a1.y, f.a1.z, f.a1.w};
    bf16x8 ah, am, al;
    split3_8(a8, ah, am, al);
    U4 bh[4], bm[4], bl[4];
#pragma unroll
    for (int et = 0; et < 4; ++et) {
      bh[et].u = f.b[et * 3 + 0];
      bm[et].u = f.b[et * 3 + 1];
      bl[et].u = f.b[et * 3 + 2];
    }
#pragma unroll
    for (int et = 0; et < 4; ++et)
      acc0[et] = __builtin_amdgcn_mfma_f32_16x16x32_bf16(ah, bh[et].s, acc0[et], 0, 0, 0);
#pragma unroll
    for (int et = 0; et < 4; ++et)
      acc1[et] = __builtin_amdgcn_mfma_f32_16x16x32_bf16(ah, bm[et].s, acc1[et], 0, 0, 0);
#pragma unroll
    for (int et = 0; et < 4; ++et)
      acc1[et] = __builtin_amdgcn_mfma_f32_16x16x32_bf16(am, bh[et].s, acc1[et], 0, 0, 0);
#pragma unroll
    for (int et = 0; et < 4; ++et)
      acc1[et] = __builtin_amdgcn_mfma_f32_16x16x32_bf16(ah, bl[et].s, acc1[et], 0, 0, 0);
#pragma unroll
    for (int et = 0; et < 4; ++et)
      acc1[et] = __builtin_amdgcn_mfma_f32_16x16x32_bf16(al, bh[et].s, acc1[et], 0, 0, 0);
#pragma unroll
    for (int et = 0; et < 4; ++et)
      acc1[et] = __builtin_amdgcn_mfma_f32_16x16x32_bf16(am, bm[et].s, acc1[et], 0, 0, 0);
  };

  stage(0); stage(1); stage(2);  // 15 loads/thread outstanding

  for (int k = 0; k < NSTEP - 3; ++k) {  // k = 0..60
    const int bb = k % 3;
    asm volatile("s_waitcnt vmcnt(10)" ::: "memory");  // slot k's 5 loads done (mine)
    __builtin_amdgcn_s_barrier();                      // everyone's slot-k loads done
    Frags f;
    loadAB(bb, f);
    asm volatile("s_waitcnt lgkmcnt(0)" ::: "memory");  // my LDS reads complete
    __builtin_amdgcn_s_barrier();                       // all waves done reading slot k
    stage(k + 3);                                       // overwrite slot k's ring pos
    crunch(f);
  }
  // tail: slots 61, 62, 63 — no more staging
  {
    asm volatile("s_waitcnt vmcnt(10)" ::: "memory");
    __builtin_amdgcn_s_barrier();
    Frags f; loadAB(61 % 3, f); crunch(f);
  }
  {
    asm volatile("s_waitcnt vmcnt(5)" ::: "memory");
    __builtin_amdgcn_s_barrier();
    Frags f; loadAB(62 % 3, f); crunch(f);
  }
  {
    asm volatile("s_waitcnt vmcnt(0)" ::: "memory");
    __builtin_amdgcn_s_barrier();
    Frags f; loadAB(63 % 3, f); crunch(f);
  }

  // epilogue: C/D layout col=lane&15, row=(lane>>4)*4+reg (HW-verified)
#pragma unroll
  for (int q = 0; q < 4; ++q) {
    float v[4];
#pragma unroll
    for (int et = 0; et < 4; ++et) v[et] = acc0[et][q] + acc1[et][q];

    float topv[K_TOP];
    int topi[K_TOP];
#pragma unroll
    for (int t = 0; t < K_TOP; ++t) {
      float bv = v[0];
      int bi = col;
#pragma unroll
      for (int et = 1; et < 4; ++et) {
        const bool take = v[et] > bv;
        bv = take ? v[et] : bv;
        bi = take ? (et * 16 + col) : bi;
      }
#pragma unroll
      for (int off = 1; off < 16; off <<= 1) {
        const float ov = __shfl_xor(bv, off, 64);
        const int oi = __shfl_xor(bi, off, 64);
        const bool take = (ov > bv) || (ov == bv && oi < bi);  // lowest idx on tie
        bv = take ? ov : bv;
        bi = take ? oi : bi;
      }
      topv[t] = bv;
      topi[t] = bi;
#pragma unroll
      for (int et = 0; et < 4; ++et)
        if (bi == et * 16 + col) v[et] = -INFINITY;
    }

    float p[K_TOP], sum = 0.f;
#pragma unroll
    for (int t = 0; t < K_TOP; ++t) {
      p[t] = expf(topv[t] - topv[0]);
      sum += p[t];
    }
    const float inv = 1.f / sum;

    const int tok = tok0 + w * 16 + kg * 4 + q;
#pragma unroll
    for (int et = 0; et < 4; ++et) {
      const int e = et * 16 + col;
      float pv = 0.f, mv = 0.f;
#pragma unroll
      for (int t = 0; t < K_TOP; ++t) {
        const bool hit = (topi[t] == e);
        pv = hit ? p[t] * inv : pv;
        mv = hit ? 1.f : mv;
      }
      Pout[(size_t)tok * E_DIM + e] = pv;
      Mout[(size_t)tok * E_DIM + e] = mv;
    }
  }
}

extern "C" void kernel_launch(void* const* d_in, const int* in_sizes, int n_in,
                              void* d_out, int out_size, void* d_ws, size_t ws_size,
                              hipStream_t stream) {
  const float* X = (const float*)d_in[0];
  const float* W = (const float*)d_in[1];
  float* P = (float*)d_out;
  float* M = P + (size_t)N_TOK * E_DIM;
  uint4* WF = (uint4*)d_ws;  // 64 * 12 * 64 * 16B = 768 KB

  wprep_kernel<<<dim3(64), dim3(256), 0, stream>>>(W, WF);
  gemm_router<<<dim3(N_TOK / BLK_TOK), dim3(256), 0, stream>>>(X, WF, P, M);
}